// Round 8
// baseline (497.340 us; speedup 1.0000x reference)
//
#include <hip/hip_runtime.h>
#include <hip/hip_bf16.h>

// 3-layer tanh RNN. B=32, T=64, D_IN=10000, H=200, N_CLASSES=2.
//
// R8:
//  * gemm: R7 was LDS-bound AND 8-way bank-conflicted (64B packed row stride;
//    SQ_LDS_BANK_CONFLICT=2.78M cyc). Rows now padded to 40 bf16 (80B stride
//    -> uniform 2-way aliasing = free) IN THE GLOBAL PACKED BUFFER, since
//    global_load_lds is strictly base+lane*16 (no scatter). A-tile LDS rows
//    padded to 40 as well. Atomic epilogue (no partial buffers).
//  * rec: (4 outputs x 28-wide aligned k-window)/thread, 8-way in-wave k-split,
//    shuffle reduce (no LDS partials), ONE raw barrier/step
//    (s_waitcnt lgkmcnt(0) + s_barrier: Hout global stores never drain).
//  * split-bf16 3-term everywhere: ~fp32 accuracy at bf16 MFMA rate.

typedef __bf16  bf16x8 __attribute__((ext_vector_type(8)));
typedef float   f32x4  __attribute__((ext_vector_type(4)));

#define HDIM 200
#define BM 128
#define ROWP 40                    // padded k-row length (bf16) -> 80B stride
#define CHUNK_ELEMS (2 * 208 * ROWP)   // hi + lo per k-chunk = 16640 bf16
#define CHUNK_16B   (CHUNK_ELEMS / 8)  // 2080 16B-chunks
#define MFMA(a, b, c) __builtin_amdgcn_mfma_f32_16x16x32_bf16(a, b, c, 0, 0, 0)

__device__ __forceinline__ void glds16(const void* g, void* l) {
    __builtin_amdgcn_global_load_lds(
        (const __attribute__((address_space(1))) unsigned int*)g,
        (__attribute__((address_space(3))) unsigned int*)l, 16, 0, 0);
}

// ---- pack W [HDIM x K] fp32 -> chunks: [kc][208 x 40 hi][208 x 40 lo] ----
__global__ void pack_w(const float* __restrict__ W, int K, int nkc,
                       __bf16* __restrict__ out)
{
    const int total = nkc * CHUNK_16B;
    for (int g = blockIdx.x * blockDim.x + threadIdx.x; g < total;
         g += gridDim.x * blockDim.x) {
        const int kc = g / CHUNK_16B;
        const int o  = g - kc * CHUNK_16B;
        const int isLo = (o >= 1040);
        const int o2 = isLo ? o - 1040 : o;   // 1040 = 208 rows * 5 chunks
        const int r  = o2 / 5;                // 0..207
        const int cq = (o2 - r * 5) * 8;      // 0,8,16,24,32
        bf16x8 v;
#pragma unroll
        for (int i = 0; i < 8; ++i) {
            const int c = cq + i;
            const int k = kc * 32 + c;
            float f = (r < HDIM && c < 32 && k < K) ? W[(size_t)r * K + k] : 0.f;
            __bf16 h = (__bf16)f;
            v[i] = isLo ? (__bf16)(f - (float)h) : h;
        }
        *(bf16x8*)&out[(size_t)g * 8] = v;
    }
}

// ---- pipelined GEMM: C[m][n] (+)= sum_k A[m][k]*W[n][k] ----
// 8 waves = 4 M-groups (2 Mtiles ea) x 2 N-groups (7/6 nt). 1 barrier/kstep.
__global__ __launch_bounds__(512, 1)
void gemm_pipe(const float* __restrict__ A, int lda, int K,
               const __bf16* __restrict__ Bpack,
               float* __restrict__ C, int ksteps, int accumulate)
{
    __shared__ alignas(16) __bf16 Ab[2][2 * 128 * ROWP];   // hi | lo, 20.5KB ea
    __shared__ alignas(16) __bf16 Bb[2][CHUNK_ELEMS];      // hi | lo, 33.3KB ea

    const int tid = threadIdx.x;
    const int kc0 = blockIdx.y * ksteps;
    const int m0  = blockIdx.x * BM;

    const int wv = tid >> 6, lane = tid & 63;
    const int r16 = lane & 15, kg = lane >> 4;
    const int mg = wv & 3, ng = wv >> 2;
    const int nt0 = ng * 7, ntw = ng ? 6 : 7;

    const int a_row = tid >> 2;          // 0..127
    const int a_q   = tid & 3;           // 8-float column group
    const float* Arow = A + (size_t)(m0 + a_row) * lda + a_q * 8;

    f32x4 acc[2][7];
#pragma unroll
    for (int mi = 0; mi < 2; ++mi)
#pragma unroll
        for (int j = 0; j < 7; ++j) acc[mi][j] = (f32x4)0.f;

    float av[8];
    auto loadA = [&](int ks) {
        const int kb = (kc0 + ks) * 32;
        if (kb + a_q * 8 < K) {          // 8-granular, K % 8 == 0
            const float* p = Arow + kb;
            float4 x0 = *(const float4*)p, x1 = *(const float4*)(p + 4);
            av[0]=x0.x; av[1]=x0.y; av[2]=x0.z; av[3]=x0.w;
            av[4]=x1.x; av[5]=x1.y; av[6]=x1.z; av[7]=x1.w;
        } else {
#pragma unroll
            for (int i = 0; i < 8; ++i) av[i] = 0.f;
        }
    };
    auto issueB = [&](int ks, int buf) {
        const char* src = (const char*)Bpack + (size_t)(kc0 + ks) * (CHUNK_16B * 16);
        char* dst = (char*)&Bb[buf][0];
#pragma unroll
        for (int r = 0; r < 4; ++r)
            glds16(src + (r * 512 + tid) * 16, dst + (r * 512 + tid) * 16);
        if (tid < 32)
            glds16(src + (2048 + tid) * 16, dst + (2048 + tid) * 16);
    };

    loadA(0);
    issueB(0, 0);

    for (int ks = 0; ks < ksteps; ++ks) {
        const int cur = ks & 1, nxt = cur ^ 1;
        // commit A regs -> LDS hi/lo (padded rows: bank-uniform 2-way)
        bf16x8 th, tl;
#pragma unroll
        for (int i = 0; i < 8; ++i) {
            __bf16 h = (__bf16)av[i];
            th[i] = h; tl[i] = (__bf16)(av[i] - (float)h);
        }
        *(bf16x8*)&Ab[cur][a_row * ROWP + a_q * 8]              = th;
        *(bf16x8*)&Ab[cur][128 * ROWP + a_row * ROWP + a_q * 8] = tl;
        __syncthreads();   // drains glds B(ks) + A commits; B(ks+1) issued after
        if (ks + 1 < ksteps) { issueB(ks + 1, nxt); loadA(ks + 1); }

        const int ao0 = (mg * 32 + r16) * ROWP + kg * 8;
        const int ao1 = ao0 + 16 * ROWP;
        bf16x8 ah0 = *(const bf16x8*)&Ab[cur][ao0];
        bf16x8 al0 = *(const bf16x8*)&Ab[cur][128 * ROWP + ao0];
        bf16x8 ah1 = *(const bf16x8*)&Ab[cur][ao1];
        bf16x8 al1 = *(const bf16x8*)&Ab[cur][128 * ROWP + ao1];
#pragma unroll
        for (int j = 0; j < 7; ++j) {
            if (j < ntw) {
                const int bo = ((nt0 + j) * 16 + r16) * ROWP + kg * 8;
                bf16x8 bh = *(const bf16x8*)&Bb[cur][bo];
                bf16x8 bl = *(const bf16x8*)&Bb[cur][208 * ROWP + bo];
                acc[0][j] = MFMA(al0, bh, acc[0][j]);
                acc[0][j] = MFMA(ah0, bl, acc[0][j]);
                acc[0][j] = MFMA(ah0, bh, acc[0][j]);
                acc[1][j] = MFMA(al1, bh, acc[1][j]);
                acc[1][j] = MFMA(ah1, bl, acc[1][j]);
                acc[1][j] = MFMA(ah1, bh, acc[1][j]);
            }
        }
    }

    // epilogue: C/D layout col=lane&15, row=(lane>>4)*4+reg
#pragma unroll
    for (int mi = 0; mi < 2; ++mi) {
        const int rb = m0 + (mg * 2 + mi) * 16 + kg * 4;
#pragma unroll
        for (int j = 0; j < 7; ++j) {
            if (j < ntw) {
                const int n = (nt0 + j) * 16 + r16;
                if (n < HDIM) {
                    if (accumulate) {
#pragma unroll
                        for (int r = 0; r < 4; ++r)
                            atomicAdd(&C[(size_t)(rb + r) * HDIM + n], acc[mi][j][r]);
                    } else {
#pragma unroll
                        for (int r = 0; r < 4; ++r)
                            C[(size_t)(rb + r) * HDIM + n] = acc[mi][j][r];
                    }
                }
            }
        }
    }
}

__device__ __forceinline__ float fast_tanh(float x) {
    float e = __expf(-2.f * fabsf(x));
    float r = (1.f - e) / (1.f + e);
    return copysignf(r, x);
}

__device__ __forceinline__ void raw_barrier() {
    // LDS-consistency barrier WITHOUT the vmcnt(0) drain of __syncthreads:
    // the per-step Hout global store stays in flight across steps.
    asm volatile("s_waitcnt lgkmcnt(0)\n\ts_barrier" ::: "memory");
}

// ---- recurrence: 1 block/batch. thread (g,s): outputs 4g..4g+3, k-window
// [base,base+28) aligned, covering slice [25s,25s+25); 8-way shuffle reduce.
__global__ __launch_bounds__(512, 1)
void rnn_rec(const float* __restrict__ pre,   // [32][64][200] (GEMM only)
             const float* __restrict__ Whh,   // [200][200]
             const float* __restrict__ bih,
             const float* __restrict__ bhh,
             float* __restrict__ Hout)        // [32][64][200]
{
    const int b   = blockIdx.x;
    const int tid = threadIdx.x;

    __shared__ float preS[64 * HDIM];          // 51.2 KB
    __shared__ float h[2][HDIM];

    {   // stage pre slab (coalesced)
        const float4* ps = (const float4*)(pre + (size_t)b * 64 * HDIM);
        float4* pd = (float4*)preS;
        for (int i = tid; i < 3200; i += 512) pd[i] = ps[i];
    }

    const int g = tid >> 3;             // 0..63 (active < 50)
    const int s = tid & 7;              // k-slice
    const bool act = (g < 50);
    const int n0 = g * 4;
    const int lo = s & 3;               // 25s - base
    const int base = 25 * s - lo;       // 4-aligned window start

    float w[4][28];
    float bv[4];
    if (act) {
#pragma unroll
        for (int jn = 0; jn < 4; ++jn) {
            const float* wr = Whh + (size_t)(n0 + jn) * HDIM;
#pragma unroll
            for (int c4 = 0; c4 < 7; ++c4) {
                float4 v = *(const float4*)(wr + base + c4 * 4);
                const float vv[4] = {v.x, v.y, v.z, v.w};
#pragma unroll
                for (int e = 0; e < 4; ++e) {
                    const int c = c4 * 4 + e;
                    w[jn][c] = (c >= lo && c < lo + 25) ? vv[e] : 0.f;
                }
            }
            if (s == 0) bv[jn] = bih[n0 + jn] + bhh[n0 + jn];
        }
    }
    if (tid < HDIM) h[0][tid] = 0.f;
    __syncthreads();

    for (int t = 0; t < 64; ++t) {
        const int cur = t & 1, nxt = cur ^ 1;
        if (act) {
            float a0 = 0.f, a1 = 0.f, a2 = 0.f, a3 = 0.f;
#pragma unroll
            for (int c4 = 0; c4 < 7; ++c4) {
                float4 hv = *(const float4*)&h[cur][base + c4 * 4];
                a0 += w[0][c4*4+0]*hv.x + w[0][c4*4+1]*hv.y + w[0][c4*4+2]*hv.z + w[0][c4*4+3]*hv.w;
                a1 += w[1][c4*4+0]*hv.x + w[1][c4*4+1]*hv.y + w[1][c4*4+2]*hv.z + w[1][c4*4+3]*hv.w;
                a2 += w[2][c4*4+0]*hv.x + w[2][c4*4+1]*hv.y + w[2][c4*4+2]*hv.z + w[2][c4*4+3]*hv.w;
                a3 += w[3][c4*4+0]*hv.x + w[3][c4*4+1]*hv.y + w[3][c4*4+2]*hv.z + w[3][c4*4+3]*hv.w;
            }
#pragma unroll
            for (int m = 1; m <= 4; m <<= 1) {
                a0 += __shfl_xor(a0, m); a1 += __shfl_xor(a1, m);
                a2 += __shfl_xor(a2, m); a3 += __shfl_xor(a3, m);
            }
            if (s == 0) {
                float4 pv = *(const float4*)&preS[t * HDIM + n0];
                float v0 = fast_tanh(a0 + pv.x + bv[0]);
                float v1 = fast_tanh(a1 + pv.y + bv[1]);
                float v2 = fast_tanh(a2 + pv.z + bv[2]);
                float v3 = fast_tanh(a3 + pv.w + bv[3]);
                *(float4*)&h[nxt][n0] = make_float4(v0, v1, v2, v3);
                *(float4*)&Hout[((size_t)b * 64 + t) * HDIM + n0] =
                    make_float4(v0, v1, v2, v3);
            }
        }
        raw_barrier();
    }
}

// ---- trivially-correct FC head ----
__global__ void fc_head(const float* __restrict__ Hlast_base,
                        const float* __restrict__ fcw,
                        const float* __restrict__ fcb,
                        float* __restrict__ out)
{
    const int i = threadIdx.x;
    if (i >= 64) return;
    const int b = i >> 1, cls = i & 1;
    const float* hp = Hlast_base + ((size_t)b * 64 + 63) * HDIM;
    const float* fw = fcw + cls * HDIM;
    float s = fcb[cls];
    for (int j = 0; j < HDIM; ++j) s += hp[j] * fw[j];
    out[b * 2 + cls] = s;
}

extern "C" void kernel_launch(void* const* d_in, const int* in_sizes, int n_in,
                              void* d_out, int out_size, void* d_ws, size_t ws_size,
                              hipStream_t stream) {
    const float* x     = (const float*)d_in[0];
    const float* W_ih0 = (const float*)d_in[1];
    const float* W_hh0 = (const float*)d_in[2];
    const float* b_ih0 = (const float*)d_in[3];
    const float* b_hh0 = (const float*)d_in[4];
    const float* W_ih1 = (const float*)d_in[5];
    const float* W_hh1 = (const float*)d_in[6];
    const float* b_ih1 = (const float*)d_in[7];
    const float* b_hh1 = (const float*)d_in[8];
    const float* W_ih2 = (const float*)d_in[9];
    const float* W_hh2 = (const float*)d_in[10];
    const float* b_ih2 = (const float*)d_in[11];
    const float* b_hh2 = (const float*)d_in[12];
    const float* fc_w  = (const float*)d_in[13];
    const float* fc_b  = (const float*)d_in[14];
    float* out = (float*)d_out;

    const size_t PE = (size_t)2048 * HDIM;          // 409600
    float* P     = (float*)d_ws;
    float* Hbuf  = P + PE;
    float* Hbuf2 = Hbuf + PE;
    __bf16* W0p  = (__bf16*)(Hbuf2 + PE);           // 320 chunks x 16640 bf16
    __bf16* W1p  = W0p + (size_t)320 * CHUNK_ELEMS; // 7 chunks
    __bf16* W2p  = W1p + (size_t)7 * CHUNK_ELEMS;
    // ws total ~16 MB

    // ---- prologue: pack weights (padded rows; pads zeroed every call) ----
    pack_w<<<1024, 256, 0, stream>>>(W_ih0, 10000, 320, W0p);
    pack_w<<<46, 256, 0, stream>>>(W_ih1, HDIM, 7, W1p);
    pack_w<<<46, 256, 0, stream>>>(W_ih2, HDIM, 7, W2p);

    // ---- layer 0: K=10000, 16-way k-split (20 ksteps), atomic accumulate ----
    hipMemsetAsync(P, 0, PE * sizeof(float), stream);
    gemm_pipe<<<dim3(16, 16), 512, 0, stream>>>(x, 10000, 10000, W0p, P, 20, 1);
    rnn_rec<<<32, 512, 0, stream>>>(P, W_hh0, b_ih0, b_hh0, Hbuf);

    // ---- layer 1: K=200, single split, plain store ----
    gemm_pipe<<<dim3(16, 1), 512, 0, stream>>>(Hbuf, HDIM, HDIM, W1p, P, 7, 0);
    rnn_rec<<<32, 512, 0, stream>>>(P, W_hh1, b_ih1, b_hh1, Hbuf2);

    // ---- layer 2 ----
    gemm_pipe<<<dim3(16, 1), 512, 0, stream>>>(Hbuf2, HDIM, HDIM, W2p, P, 7, 0);
    rnn_rec<<<32, 512, 0, stream>>>(P, W_hh2, b_ih2, b_hh2, Hbuf);

    // ---- FC head ----
    fc_head<<<1, 64, 0, stream>>>(Hbuf, fc_w, fc_b, out);
}